// Round 1
// baseline (533.892 us; speedup 1.0000x reference)
//
#include <hip/hip_runtime.h>

// Problem constants (fixed by setup_inputs): B=64, H=W=1024, p=64.
#define BATCH   64
#define HEIGHT  1024
#define WIDTH   1024
#define PSZ     64
#define NPH     16              // HEIGHT / PSZ
#define NPW     16              // WIDTH / PSZ
#define NPATCH  (NPH * NPW)     // 256 patches per image

// Kernel 1: one block per patch. 256 threads, each loads 4 float4 per input.
// Patch row = 64 contiguous floats = 16 float4; lanes 0..15 cover one row
// segment (256 B contiguous) -> coalesced. Wave shuffle-reduce + LDS combine.
__global__ __launch_bounds__(256) void patch_mean_abs_kernel(
    const float* __restrict__ out_p, const float* __restrict__ tgt_p,
    float* __restrict__ patch_l1)
{
    const int blk   = blockIdx.x;          // [0, BATCH*NPATCH)
    const int b     = blk >> 8;            // image index
    const int patch = blk & 255;
    const int ph    = patch >> 4;
    const int pw    = patch & 15;

    const size_t base = (size_t)b * (HEIGHT * (size_t)WIDTH)
                      + (size_t)ph * PSZ * WIDTH
                      + (size_t)pw * PSZ;

    const int tid = threadIdx.x;
    const int r0  = tid >> 4;              // 0..15 : starting patch row
    const int c4  = (tid & 15) * 4;        // float offset within patch row

    float s = 0.f;
#pragma unroll
    for (int rr = 0; rr < 4; ++rr) {
        const size_t off = base + (size_t)(r0 + rr * 16) * WIDTH + c4;
        const float4 o = *reinterpret_cast<const float4*>(out_p + off);
        const float4 t = *reinterpret_cast<const float4*>(tgt_p + off);
        s += fabsf(o.x - t.x) + fabsf(o.y - t.y)
           + fabsf(o.z - t.z) + fabsf(o.w - t.w);
    }

    // wave(64)-level tree reduction
#pragma unroll
    for (int off = 32; off > 0; off >>= 1)
        s += __shfl_down(s, off, 64);

    __shared__ float lds[4];
    if ((tid & 63) == 0) lds[tid >> 6] = s;
    __syncthreads();
    if (tid == 0) {
        const float tot = lds[0] + lds[1] + lds[2] + lds[3];
        patch_l1[blk] = tot * (1.0f / (PSZ * PSZ));   // per-patch mean
    }
}

// Kernel 2: single block. For each image, block-max over its 256 patch means;
// accumulate, then write mean over images. 16K loads total -> negligible.
__global__ __launch_bounds__(256) void finalize_kernel(
    const float* __restrict__ patch_l1, float* __restrict__ result)
{
    __shared__ float lds[4];
    const int tid = threadIdx.x;
    float acc = 0.f;

    for (int img = 0; img < BATCH; ++img) {
        float v = patch_l1[img * NPATCH + tid];
#pragma unroll
        for (int off = 32; off > 0; off >>= 1)
            v = fmaxf(v, __shfl_down(v, off, 64));
        if ((tid & 63) == 0) lds[tid >> 6] = v;
        __syncthreads();
        if (tid == 0)
            acc += fmaxf(fmaxf(lds[0], lds[1]), fmaxf(lds[2], lds[3]));
        __syncthreads();   // protect lds reuse next iteration
    }
    if (tid == 0) result[0] = acc * (1.0f / BATCH);
}

extern "C" void kernel_launch(void* const* d_in, const int* in_sizes, int n_in,
                              void* d_out, int out_size, void* d_ws, size_t ws_size,
                              hipStream_t stream) {
    const float* out_p = (const float*)d_in[0];
    const float* tgt_p = (const float*)d_in[1];
    // d_in[2] is patch_size (=64), baked into the kernel constants.
    float* patch_l1 = (float*)d_ws;        // 16384 floats = 64 KB scratch
    float* result   = (float*)d_out;

    patch_mean_abs_kernel<<<BATCH * NPATCH, 256, 0, stream>>>(out_p, tgt_p, patch_l1);
    finalize_kernel<<<1, 256, 0, stream>>>(patch_l1, result);
}

// Round 2
// 500.934 us; speedup vs baseline: 1.0658x; 1.0658x over previous
//
#include <hip/hip_runtime.h>

// Problem constants (fixed by setup_inputs): B=64, H=W=1024, p=64.
#define BATCH   64
#define HEIGHT  1024
#define WIDTH   1024
#define PSZ     64
#define NPH     16              // HEIGHT / PSZ
#define NPW     16              // WIDTH / PSZ

// Kernel 1: one block per (image, patch-row). 1024 blocks x 256 threads.
// Thread t covers columns 4t..4t+3 for 64 consecutive rows -> each iteration
// the block reads two fully-contiguous 4 KB rows (o and t). Patch identity is
// tid>>4, so a width-16 shuffle reduce yields all 16 patch sums without LDS.
// Block then writes max-of-16-patch-means to ws[block].
__global__ __launch_bounds__(256) void patch_rowstrip_kernel(
    const float* __restrict__ out_p, const float* __restrict__ tgt_p,
    float* __restrict__ blk_max)
{
    const int blk  = blockIdx.x;           // [0, BATCH*NPH)
    const int img  = blk >> 4;
    const int prow = blk & 15;

    const size_t base = (size_t)img * (HEIGHT * (size_t)WIDTH)
                      + (size_t)prow * PSZ * WIDTH
                      + (size_t)threadIdx.x * 4;

    const float4* __restrict__ po = reinterpret_cast<const float4*>(out_p + base);
    const float4* __restrict__ pt = reinterpret_cast<const float4*>(tgt_p + base);
    const int row_stride_f4 = WIDTH / 4;   // 256 float4 per row

    float s0 = 0.f, s1 = 0.f;
#pragma unroll 8
    for (int r = 0; r < PSZ; ++r) {
        const float4 a = po[(size_t)r * row_stride_f4];
        const float4 c = pt[(size_t)r * row_stride_f4];
        s0 += fabsf(a.x - c.x) + fabsf(a.y - c.y);
        s1 += fabsf(a.z - c.z) + fabsf(a.w - c.w);
    }
    float s = s0 + s1;

    // width-16 segment reduce: lanes with (tid&15)==0 hold full patch sums
#pragma unroll
    for (int off = 8; off > 0; off >>= 1)
        s += __shfl_down(s, off, 16);

    __shared__ float lds[NPW];
    if ((threadIdx.x & 15) == 0) lds[threadIdx.x >> 4] = s;
    __syncthreads();
    if (threadIdx.x == 0) {
        float m = lds[0];
#pragma unroll
        for (int i = 1; i < NPW; ++i) m = fmaxf(m, lds[i]);
        blk_max[blk] = m * (1.0f / (PSZ * PSZ));   // max of patch means in strip
    }
}

// Kernel 2: single 256-thread block. blk_max has 1024 entries laid out as
// [img*16 + prow]. Thread t loads float4 covering 4 strips of image t>>2;
// width-4 shuffle max -> image max on (t&3)==0; wave-wide sum of leader
// values + LDS across 4 waves -> mean over 64 images.
__global__ __launch_bounds__(256) void final_reduce_kernel(
    const float* __restrict__ blk_max, float* __restrict__ result)
{
    const int t = threadIdx.x;
    const float4 v = reinterpret_cast<const float4*>(blk_max)[t];
    float m = fmaxf(fmaxf(v.x, v.y), fmaxf(v.z, v.w));
    m = fmaxf(m, __shfl_down(m, 2, 4));
    m = fmaxf(m, __shfl_down(m, 1, 4));
    float contrib = ((t & 3) == 0) ? m : 0.0f;   // image max, once per image
#pragma unroll
    for (int off = 32; off > 0; off >>= 1)
        contrib += __shfl_down(contrib, off, 64);

    __shared__ float lds[4];
    if ((t & 63) == 0) lds[t >> 6] = contrib;
    __syncthreads();
    if (t == 0)
        result[0] = (lds[0] + lds[1] + lds[2] + lds[3]) * (1.0f / BATCH);
}

extern "C" void kernel_launch(void* const* d_in, const int* in_sizes, int n_in,
                              void* d_out, int out_size, void* d_ws, size_t ws_size,
                              hipStream_t stream) {
    const float* out_p = (const float*)d_in[0];
    const float* tgt_p = (const float*)d_in[1];
    // d_in[2] is patch_size (=64), baked into kernel constants.
    float* blk_max = (float*)d_ws;         // 1024 floats = 4 KB scratch
    float* result  = (float*)d_out;

    patch_rowstrip_kernel<<<BATCH * NPH, 256, 0, stream>>>(out_p, tgt_p, blk_max);
    final_reduce_kernel<<<1, 256, 0, stream>>>(blk_max, result);
}